// Round 16
// baseline (91.876 us; speedup 1.0000x reference)
//
#include <hip/hip_runtime.h>
#include <hip/hip_bf16.h>
#include <math.h>

typedef __bf16 bf16_t;
typedef __bf16 bf16x8 __attribute__((ext_vector_type(8)));
typedef __bf16 bf16x4 __attribute__((ext_vector_type(4)));
typedef float  f32x4  __attribute__((ext_vector_type(4)));

#define MFMA16(a, b, c) __builtin_amdgcn_mfma_f32_16x16x32_bf16((a), (b), (c), 0, 0, 0)
#define GLDS16(g, s) __builtin_amdgcn_global_load_lds( \
    (const __attribute__((address_space(1))) void*)(g), \
    (__attribute__((address_space(3))) void*)(s), 16, 0, 0)

#define LOG2E 1.4426950408889634f

// ---------------------------------------------------------------------------
// K0: merged PREP kernel (bias fragment table | GroupNorm | weight cast).
// ---------------------------------------------------------------------------
__global__ __launch_bounds__(512) void prep_kernel(
    const float* __restrict__ wq, const float* __restrict__ wk,
    const float* __restrict__ wv, const float* __restrict__ wp,
    bf16_t* __restrict__ Wqkv, bf16_t* __restrict__ Wp,
    const float* __restrict__ pos, bf16_t* __restrict__ Bias2,
    const float* __restrict__ x, const float* __restrict__ gamma,
    const float* __restrict__ beta, bf16_t* __restrict__ xnT)
{
    const int blk = blockIdx.x;
    const int t = threadIdx.x;
    __shared__ __align__(16) char pshm[4096];

    if (blk < 512) {
        // Bias2[h][qt(64)][kt(64)][lane(64)][j(4)], *log2e (swapped C-layout)
        bf16_t* ps = (bf16_t*)pshm;     // [32][64]
        const int h   = blk >> 6;
        const int qt  = blk & 63;
        const int qy  = qt >> 1;
        const int qxb = (qt & 1) * 16;
        for (int i = t; i < 32 * 63; i += 512) {
            const int r = i / 63, dx = i - r * 63;
            ps[r * 64 + dx] = (bf16_t)(pos[h * 3969 + (qy + r) * 63 + dx] * LOG2E);
        }
        __syncthreads();
        bf16_t* outb = Bias2 + (((size_t)h * 64 + qt) * 64) * 256;
#pragma unroll
        for (int it = 0; it < 8; ++it) {
            const int idx = t + it * 512;
            const int kt = idx >> 6, l = idx & 63;
            const int qx  = qxb + (l & 15);
            const int nk0 = kt * 16 + (l >> 4) * 4;
            const int ky = nk0 >> 5;
            const int kx0 = nk0 & 31;
            const int r = 31 - ky;
            const int dx0 = qx - kx0 + 31;
            bf16x4 o;
#pragma unroll
            for (int j = 0; j < 4; ++j) o[j] = ps[r * 64 + dx0 - j];
            *(bf16x4*)(outb + (size_t)idx * 4) = o;
        }
    } else if (blk < 768) {
        // GroupNorm, single-sweep register-resident
        float* red = (float*)pshm;
        const int bgn = blk - 512;
        const int b = bgn >> 5, g = bgn & 31;
        const int hi = t >> 8, tl = t & 255;
        const float* base = x + ((size_t)b * 512 + g * 16) * 1024;

        f32x4 v[8];
        float s = 0.f, s2 = 0.f;
#pragma unroll
        for (int it = 0; it < 8; ++it) {
            v[it] = *(const f32x4*)(base + (size_t)hi * 8192 + it * 1024 + tl * 4);
#pragma unroll
            for (int j = 0; j < 4; ++j) { s += v[it][j]; s2 += v[it][j] * v[it][j]; }
        }
#pragma unroll
        for (int m = 1; m < 64; m <<= 1) { s += __shfl_xor(s, m); s2 += __shfl_xor(s2, m); }
        const int w = t >> 6;
        if ((t & 63) == 0) { red[w] = s; red[8 + w] = s2; }
        __syncthreads();
        s = 0.f; s2 = 0.f;
#pragma unroll
        for (int i = 0; i < 8; ++i) { s += red[i]; s2 += red[8 + i]; }
        const float mean = s * (1.f / 16384.f);
        const float var  = fmaxf(s2 * (1.f / 16384.f) - mean * mean, 0.f);
        const float rstd = rsqrtf(var + 1e-6f);

        float ga[8], be[8];
#pragma unroll
        for (int it = 0; it < 8; ++it) {
            const int gc = g * 16 + hi * 8 + it;
            ga[it] = gamma[gc] * rstd;
            be[it] = beta[gc] - mean * ga[it];
        }
#pragma unroll
        for (int j = 0; j < 4; ++j) {
            bf16x8 o;
#pragma unroll
            for (int it = 0; it < 8; ++it)
                o[it] = (bf16_t)(v[it][j] * ga[it] + be[it]);
            *(bf16x8*)(xnT + ((size_t)b * 1024 + tl * 4 + j) * 512 + g * 16 + hi * 8) = o;
        }
    } else {
        // weight cast fp32 -> bf16
        const int i = ((blk - 768) * 512 + t) * 4;
#pragma unroll
        for (int j = 0; j < 4; ++j) {
            Wqkv[i + j]          = (bf16_t)wq[i + j];
            Wqkv[262144 + i + j] = (bf16_t)wk[i + j];
            Wqkv[524288 + i + j] = (bf16_t)wv[i + j];
            Wp[i + j]            = (bf16_t)wp[i + j];
        }
    }
}

// ---------------------------------------------------------------------------
// K2/K4: GEMM (unchanged — 3-buffer ring + counted vmcnt).
// ---------------------------------------------------------------------------
__global__ __launch_bounds__(256) void gemm_bt(
    const bf16_t* __restrict__ A, const bf16_t* __restrict__ Bt, int mode,
    int mtiles,
    const float* __restrict__ bias0, const float* __restrict__ bias1,
    const float* __restrict__ bias2,
    const float* __restrict__ x0, float* __restrict__ outF,
    bf16_t* __restrict__ Qb, bf16_t* __restrict__ Kb, bf16_t* __restrict__ Vb)
{
    const int K  = 512;
    const int g  = blockIdx.x;
    const int xcd = g & 7;
    const int i_  = g >> 3;
    const int m_idx = i_ % mtiles;
    const int n_idx = xcd * 8 + i_ / mtiles;
    const int m0 = m_idx * 128;
    const int n0 = n_idx * 128;
    const int t = threadIdx.x;
    const int l = t & 63, w = t >> 6;
    const int wr = w >> 1, wc = w & 1;
    const int lrow = l & 15, lgrp = l >> 4;

    __shared__ __align__(16) char smem_raw[49152];
    bf16_t* Ct = (bf16_t*)smem_raw;           // [128][136] (34816 B)

    f32x4 acc[4][4];
#pragma unroll
    for (int i = 0; i < 4; ++i)
#pragma unroll
        for (int j = 0; j < 4; ++j) acc[i][j] = (f32x4){0.f, 0.f, 0.f, 0.f};

    const bf16_t* gA0 = A  + (size_t)(m0 + w * 16 + (l >> 2)) * K + (l & 3) * 8;
    const bf16_t* gA1 = gA0 + (size_t)64 * K;
    const bf16_t* gB0 = Bt + (size_t)(n0 + w * 16 + (l >> 2)) * K + (l & 3) * 8;
    const bf16_t* gB1 = gB0 + (size_t)64 * K;

#define STAGE(s, k0) do {                                                   \
    bf16_t* As_ = (bf16_t*)(smem_raw + (s) * 16384);                        \
    bf16_t* Bs_ = (bf16_t*)(smem_raw + (s) * 16384 + 8192);                 \
    GLDS16(gA0 + (k0), As_ + w * 512);                                      \
    GLDS16(gA1 + (k0), As_ + 2048 + w * 512);                               \
    GLDS16(gB0 + (k0), Bs_ + w * 512);                                      \
    GLDS16(gB1 + (k0), Bs_ + 2048 + w * 512); } while (0)

    STAGE(0, 0);
    STAGE(1, 32);

#pragma unroll
    for (int tk = 0; tk < 16; ++tk) {
        if (tk < 15) asm volatile("s_waitcnt vmcnt(4)" ::: "memory");
        else         asm volatile("s_waitcnt vmcnt(0)" ::: "memory");
        __builtin_amdgcn_s_barrier();
        __builtin_amdgcn_sched_barrier(0);
        if (tk + 2 < 16) STAGE((tk + 2) % 3, (tk + 2) * 32);
        const bf16_t* Asb = (const bf16_t*)(smem_raw + (tk % 3) * 16384);
        const bf16_t* Bsb = Asb + 4096;
        bf16x8 af[4], bfr[4];
#pragma unroll
        for (int ms = 0; ms < 4; ++ms)
            af[ms] = *(const bf16x8*)&Asb[(wr * 64 + ms * 16 + lrow) * 32 + lgrp * 8];
#pragma unroll
        for (int ns = 0; ns < 4; ++ns)
            bfr[ns] = *(const bf16x8*)&Bsb[(wc * 64 + ns * 16 + lrow) * 32 + lgrp * 8];
        __builtin_amdgcn_s_setprio(1);
#pragma unroll
        for (int ms = 0; ms < 4; ++ms)
#pragma unroll
            for (int ns = 0; ns < 4; ++ns)
                acc[ms][ns] = MFMA16(af[ms], bfr[ns], acc[ms][ns]);
        __builtin_amdgcn_s_setprio(0);
    }
#undef STAGE

    if (mode == 0) {
        const int which = m0 >> 9;
        const int mq = (m0 >> 7) & 3;
        const float* bias = (which == 0) ? bias0 : (which == 1) ? bias1 : bias2;
        const float scl = (which == 0) ? 0.125f * LOG2E : 1.0f;
        const int b   = n_idx >> 3;
        const int nn0 = (n_idx & 7) * 128;

        __syncthreads();
        if (which < 2) {
            bf16_t* Qk = (which == 0) ? Qb : Kb;
#pragma unroll
            for (int ms = 0; ms < 4; ++ms) {
                const int ml = wr * 64 + ms * 16 + lgrp * 4;
#pragma unroll
                for (int ns = 0; ns < 4; ++ns) {
                    const int nl = wc * 64 + ns * 16 + lrow;
                    bf16x4 pk;
#pragma unroll
                    for (int j = 0; j < 4; ++j)
                        pk[j] = (bf16_t)((acc[ms][ns][j] + bias[mq * 128 + ml + j]) * scl);
                    *(bf16x4*)&Ct[nl * 136 + ml] = pk;
                }
            }
            __syncthreads();
#pragma unroll
            for (int it = 0; it < 8; ++it) {
                const int idx = it * 256 + t;
                const int token = idx >> 4, oc = idx & 15;
                const bf16x8 vv8 = *(const bf16x8*)&Ct[token * 136 + oc * 8];
                const int head = mq * 2 + (oc >> 3);
                const int d = (oc & 7) * 8;
                *(bf16x8*)(Qk + (((size_t)b * 8 + head) * 1024 + nn0 + token) * 64 + d) = vv8;
            }
        } else {
#pragma unroll
            for (int ms = 0; ms < 4; ++ms) {
                const int ml = wr * 64 + ms * 16 + lgrp * 4;
#pragma unroll
                for (int ns = 0; ns < 4; ++ns) {
                    const int nl = wc * 64 + ns * 16 + lrow;
#pragma unroll
                    for (int j = 0; j < 4; ++j)
                        Ct[(ml + j) * 136 + nl] =
                            (bf16_t)(acc[ms][ns][j] + bias[mq * 128 + ml + j]);
                }
            }
            __syncthreads();
#pragma unroll
            for (int it = 0; it < 8; ++it) {
                const int idx = it * 256 + t;
                const int o = idx >> 4, nc = idx & 15;
                const bf16x8 vv8 = *(const bf16x8*)&Ct[o * 136 + nc * 8];
                const int head = mq * 2 + (o >> 6);
                const int d = o & 63;
                *(bf16x8*)(Vb + (((size_t)b * 8 + head) * 64 + d) * 1024 + nn0 + nc * 8) = vv8;
            }
        }
    } else {
#pragma unroll
        for (int ms = 0; ms < 4; ++ms) {
#pragma unroll
            for (int ns = 0; ns < 4; ++ns) {
                const int c  = m0 + wr * 64 + ms * 16 + lgrp * 4;
                const int np = n0 + wc * 64 + ns * 16 + lrow;
                const int b = np >> 10, n = np & 1023;
#pragma unroll
                for (int j = 0; j < 4; ++j) {
                    const size_t idx = ((size_t)b * 512 + c + j) * 1024 + n;
                    outF[idx] = acc[ms][ns][j] + bias0[c + j] + x0[idx];
                }
            }
        }
    }
}

// ---------------------------------------------------------------------------
// K3: fused attention — r11's 16x16 compute path, NK-SPLIT + GRID GROWTH:
// 8 waves = 4 q-chunks (qc=w&3, 16 q each) x 2 nk-halves (half=w>>2).
// Block covers 64 q; grid (64, 16) = 1024 blocks -> 3 blocks/CU resident
// (LDS 54,272 x 3 = 162,816 <= 163,840) = 24 waves/CU (was grid-capped at 16).
// Each wave computes its nk-half (one st per double-tile); partner waves
// combine partial O/ts via LDS overlay at the end (exact softmax: plain sums).
// ---------------------------------------------------------------------------
__global__ __launch_bounds__(512) void attn_kernel(
    const bf16_t* __restrict__ Qb, const bf16_t* __restrict__ Kb,
    const bf16_t* __restrict__ Vb, const bf16_t* __restrict__ Bias2,
    bf16_t* __restrict__ Xo)
{
    const int bh = blockIdx.x;
    const int h  = bh & 7;
    const int q0 = blockIdx.y * 64;
    const int t = threadIdx.x;
    const int w = t >> 6, l = t & 63;
    const int qc = w & 3, half = w >> 2;
    const int lrow = l & 15, lgrp = l >> 4;

    __shared__ __align__(16) char smem[54272];
    bf16_t* Ks = (bf16_t*)smem;               // [128][72]  (18432 B)
    bf16_t* Vs = (bf16_t*)(smem + 18432);     // [64][136]  (17408 B)
    bf16_t* Ps = (bf16_t*)(smem + 35840);     // [8][16][72](18432 B)
    float*  comb = (float*)smem;              // [4][64][20] overlay (20480 B)

    const int qrow = q0 + qc * 16 + lrow;
    const bf16_t* qbase = Qb + ((size_t)bh * 1024 + qrow) * 64;
    const bf16x8 qf0 = *(const bf16x8*)(qbase + lgrp * 8);
    const bf16x8 qf1 = *(const bf16x8*)(qbase + 32 + lgrp * 8);

    // qt = q0/16 + qc; wave's kt(16) tiles per double-tile it: it*8 + half*4 + k
    const bf16_t* bb = Bias2 + (((size_t)h * 64 + (q0 >> 4) + qc) * 64) * 256;

    bf16x8 ones;
#pragma unroll
    for (int i = 0; i < 8; ++i) ones[i] = (bf16_t)1.0f;

    f32x4 oacc[4], tsacc = (f32x4){0.f, 0.f, 0.f, 0.f};
#pragma unroll
    for (int j = 0; j < 4; ++j) oacc[j] = (f32x4){0.f, 0.f, 0.f, 0.f};

    const int sr2 = t >> 3;
    const int sc2 = (t & 7) * 8;
    const bf16_t* Kg = Kb + ((size_t)bh * 1024 + sr2) * 64 + sc2;   // [nk][d]
    const bf16_t* Vg = Vb + ((size_t)bh * 64 + sr2) * 1024 + sc2;   // [d][nk]

    // prologue: prefetch double-tile 0 (K 128 rows, V 128 cols) + bias x4
    bf16x8 kv0 = *(const bf16x8*)(Kg);
    bf16x8 kv1 = *(const bf16x8*)(Kg + (size_t)64 * 64);
    bf16x8 vv0 = *(const bf16x8*)(Vg);
    bf16x8 vv1 = *(const bf16x8*)(Vg + 64);
    bf16x4 bA[4], bB[4];
#pragma unroll
    for (int k = 0; k < 4; ++k)
        bA[k] = *(const bf16x4*)(bb + (size_t)((half * 4 + k) * 64 + l) * 4);

    auto dtile = [&](int it, bf16x4 (&bcur)[4], bf16x4 (&bnxt)[4]) {
        __syncthreads();                 // prev double-tile's LDS reads done
        *(bf16x8*)&Ks[sr2 * 72 + sc2]        = kv0;
        *(bf16x8*)&Ks[(64 + sr2) * 72 + sc2] = kv1;
        *(bf16x8*)&Vs[sr2 * 136 + sc2]       = vv0;
        *(bf16x8*)&Vs[sr2 * 136 + 64 + sc2]  = vv1;
        __syncthreads();                 // LDS visible to all waves
        if (it < 7) {                    // prefetch double-tile it+1 (bias, K/V)
            const int nkn = (it + 1) * 128;
#pragma unroll
            for (int k = 0; k < 4; ++k)
                bnxt[k] = *(const bf16x4*)(bb + (size_t)(((it + 1) * 8 + half * 4 + k) * 64 + l) * 4);
            kv0 = *(const bf16x8*)(Kg + (size_t)nkn * 64);
            kv1 = *(const bf16x8*)(Kg + (size_t)(nkn + 64) * 64);
            vv0 = *(const bf16x8*)(Vg + nkn);
            vv1 = *(const bf16x8*)(Vg + nkn + 64);
        }

        // this wave's nk-half: st = half
        // S^T = K Q^T (+bias from regs):  D[row = nk_local][col = q]
        f32x4 s[4];
#pragma unroll
        for (int ns = 0; ns < 4; ++ns) {
            const bf16x4 bc = bcur[ns];
            f32x4 z = (f32x4){(float)bc[0], (float)bc[1],
                              (float)bc[2], (float)bc[3]};
            const bf16x8 kf0 = *(const bf16x8*)&Ks[(half * 64 + ns * 16 + lrow) * 72 + lgrp * 8];
            const bf16x8 kf1 = *(const bf16x8*)&Ks[(half * 64 + ns * 16 + lrow) * 72 + 32 + lgrp * 8];
            z = MFMA16(kf0, qf0, z);
            z = MFMA16(kf1, qf1, z);
            s[ns] = z;
        }
        // p = exp2(s); pack to Ps[q][nk]
#pragma unroll
        for (int ns = 0; ns < 4; ++ns) {
            bf16x4 pk;
            pk[0] = (bf16_t)exp2f(s[ns][0]);
            pk[1] = (bf16_t)exp2f(s[ns][1]);
            pk[2] = (bf16_t)exp2f(s[ns][2]);
            pk[3] = (bf16_t)exp2f(s[ns][3]);
            *(bf16x4*)&Ps[(w * 16 + lrow) * 72 + ns * 16 + lgrp * 4] = pk;
        }
        const bf16x8 pf0 = *(const bf16x8*)&Ps[(w * 16 + lrow) * 72 + lgrp * 8];
        const bf16x8 pf1 = *(const bf16x8*)&Ps[(w * 16 + lrow) * 72 + 32 + lgrp * 8];
        // ts(q) += sum_nk P  (ones-A MFMA)
        tsacc = MFMA16(ones, pf0, tsacc);
        tsacc = MFMA16(ones, pf1, tsacc);
        // PV:  out^T[d][q] += V^T[d][nk] * P^T[nk][q]
#pragma unroll
        for (int ds = 0; ds < 4; ++ds) {
            const bf16x8 vf0 = *(const bf16x8*)&Vs[(ds * 16 + lrow) * 136 + half * 64 + lgrp * 8];
            const bf16x8 vf1 = *(const bf16x8*)&Vs[(ds * 16 + lrow) * 136 + half * 64 + 32 + lgrp * 8];
            oacc[ds] = MFMA16(vf0, pf0, oacc[ds]);
            oacc[ds] = MFMA16(vf1, pf1, oacc[ds]);
        }
    };

    for (int it2 = 0; it2 < 8; it2 += 2) {
        dtile(it2,     bA, bB);
        dtile(it2 + 1, bB, bA);
    }

    // combine nk-halves: waves 4-7 publish partials; waves 0-3 reduce + store
    __syncthreads();                      // all compute done; Ks/Vs free
    if (half == 1) {
        float* p = comb + ((size_t)qc * 64 + l) * 20;
#pragma unroll
        for (int ds = 0; ds < 4; ++ds)
            *(f32x4*)(p + ds * 4) = oacc[ds];
        p[16] = tsacc[0];
    }
    __syncthreads();
    if (half == 0) {
        const float* p = comb + ((size_t)qc * 64 + l) * 20;
#pragma unroll
        for (int ds = 0; ds < 4; ++ds) {
            const f32x4 o2 = *(const f32x4*)(p + ds * 4);
#pragma unroll
            for (int j = 0; j < 4; ++j) oacc[ds][j] += o2[j];
        }
        const float inv = 1.0f / (tsacc[0] + p[16]);

        const int b = bh >> 3;
        const int q = q0 + qc * 16 + lrow;
        bf16_t* xrow = Xo + ((size_t)b * 1024 + q) * 512 + h * 64;
#pragma unroll
        for (int ds = 0; ds < 4; ++ds) {
            bf16x4 o4;
#pragma unroll
            for (int j = 0; j < 4; ++j) o4[j] = (bf16_t)(oacc[ds][j] * inv);
            *(bf16x4*)(xrow + ds * 16 + lgrp * 4) = o4;
        }
    }
}

// ---------------------------------------------------------------------------
extern "C" void kernel_launch(void* const* d_in, const int* in_sizes, int n_in,
                              void* d_out, int out_size, void* d_ws, size_t ws_size,
                              hipStream_t stream)
{
    const float* x     = (const float*)d_in[0];
    const float* gamma = (const float*)d_in[3];
    const float* beta  = (const float*)d_in[4];
    const float* wq    = (const float*)d_in[5];
    const float* bq    = (const float*)d_in[6];
    const float* wk    = (const float*)d_in[7];
    const float* bk    = (const float*)d_in[8];
    const float* wv    = (const float*)d_in[9];
    const float* bv    = (const float*)d_in[10];
    const float* wp    = (const float*)d_in[11];
    const float* bp    = (const float*)d_in[12];
    const float* pos   = (const float*)d_in[13];
    float* out = (float*)d_out;

    size_t off = 0;
    char* wsb = (char*)d_ws;
    auto alloc = [&](size_t bytes) { char* p = wsb + off; off += bytes; return p; };
    bf16_t* Wqkv  = (bf16_t*)alloc((size_t)1536 * 512 * 2);
    bf16_t* Wp    = (bf16_t*)alloc((size_t)512 * 512 * 2);
    bf16_t* xnT   = (bf16_t*)alloc((size_t)8192 * 512 * 2);
    bf16_t* Qb    = (bf16_t*)alloc((size_t)8192 * 512 * 2);
    bf16_t* Kb    = (bf16_t*)alloc((size_t)8192 * 512 * 2);
    bf16_t* Vb    = (bf16_t*)alloc((size_t)8192 * 512 * 2);
    bf16_t* Xo    = (bf16_t*)alloc((size_t)8192 * 512 * 2);
    bf16_t* Bias2 = (bf16_t*)alloc((size_t)8 * 64 * 64 * 64 * 4 * 2);

    hipLaunchKernelGGL(prep_kernel, dim3(896), dim3(512), 0, stream,
                       wq, wk, wv, wp, Wqkv, Wp, pos, Bias2,
                       x, gamma, beta, xnT);
    hipLaunchKernelGGL(gemm_bt, dim3(768), dim3(256), 0, stream,
                       Wqkv, xnT, 0, 12, bq, bk, bv,
                       nullptr, nullptr, Qb, Kb, Vb);
    hipLaunchKernelGGL(attn_kernel, dim3(64, 16), dim3(512), 0, stream,
                       Qb, Kb, Vb, Bias2, Xo);
    hipLaunchKernelGGL(gemm_bt, dim3(256), dim3(256), 0, stream,
                       Wp, Xo, 1, 4, bp, nullptr, nullptr,
                       x, out, nullptr, nullptr, nullptr);
}

// Round 17
// 86.115 us; speedup vs baseline: 1.0669x; 1.0669x over previous
//
#include <hip/hip_runtime.h>
#include <hip/hip_bf16.h>
#include <math.h>

typedef __bf16 bf16_t;
typedef __bf16 bf16x8 __attribute__((ext_vector_type(8)));
typedef __bf16 bf16x4 __attribute__((ext_vector_type(4)));
typedef float  f32x4  __attribute__((ext_vector_type(4)));

#define MFMA16(a, b, c) __builtin_amdgcn_mfma_f32_16x16x32_bf16((a), (b), (c), 0, 0, 0)
#define GLDS16(g, s) __builtin_amdgcn_global_load_lds( \
    (const __attribute__((address_space(1))) void*)(g), \
    (__attribute__((address_space(3))) void*)(s), 16, 0, 0)

#define LOG2E 1.4426950408889634f

// ---------------------------------------------------------------------------
// K0: merged PREP kernel (bias fragment table | GroupNorm | weight cast).
// ---------------------------------------------------------------------------
__global__ __launch_bounds__(512) void prep_kernel(
    const float* __restrict__ wq, const float* __restrict__ wk,
    const float* __restrict__ wv, const float* __restrict__ wp,
    bf16_t* __restrict__ Wqkv, bf16_t* __restrict__ Wp,
    const float* __restrict__ pos, bf16_t* __restrict__ Bias2,
    const float* __restrict__ x, const float* __restrict__ gamma,
    const float* __restrict__ beta, bf16_t* __restrict__ xnT)
{
    const int blk = blockIdx.x;
    const int t = threadIdx.x;
    __shared__ __align__(16) char pshm[4096];

    if (blk < 512) {
        // Bias2[h][qt(64)][kt(64)][lane(64)][j(4)], *log2e (swapped C-layout)
        bf16_t* ps = (bf16_t*)pshm;     // [32][64]
        const int h   = blk >> 6;
        const int qt  = blk & 63;
        const int qy  = qt >> 1;
        const int qxb = (qt & 1) * 16;
        for (int i = t; i < 32 * 63; i += 512) {
            const int r = i / 63, dx = i - r * 63;
            ps[r * 64 + dx] = (bf16_t)(pos[h * 3969 + (qy + r) * 63 + dx] * LOG2E);
        }
        __syncthreads();
        bf16_t* outb = Bias2 + (((size_t)h * 64 + qt) * 64) * 256;
#pragma unroll
        for (int it = 0; it < 8; ++it) {
            const int idx = t + it * 512;
            const int kt = idx >> 6, l = idx & 63;
            const int qx  = qxb + (l & 15);
            const int nk0 = kt * 16 + (l >> 4) * 4;
            const int ky = nk0 >> 5;
            const int kx0 = nk0 & 31;
            const int r = 31 - ky;
            const int dx0 = qx - kx0 + 31;
            bf16x4 o;
#pragma unroll
            for (int j = 0; j < 4; ++j) o[j] = ps[r * 64 + dx0 - j];
            *(bf16x4*)(outb + (size_t)idx * 4) = o;
        }
    } else if (blk < 768) {
        // GroupNorm, single-sweep register-resident
        float* red = (float*)pshm;
        const int bgn = blk - 512;
        const int b = bgn >> 5, g = bgn & 31;
        const int hi = t >> 8, tl = t & 255;
        const float* base = x + ((size_t)b * 512 + g * 16) * 1024;

        f32x4 v[8];
        float s = 0.f, s2 = 0.f;
#pragma unroll
        for (int it = 0; it < 8; ++it) {
            v[it] = *(const f32x4*)(base + (size_t)hi * 8192 + it * 1024 + tl * 4);
#pragma unroll
            for (int j = 0; j < 4; ++j) { s += v[it][j]; s2 += v[it][j] * v[it][j]; }
        }
#pragma unroll
        for (int m = 1; m < 64; m <<= 1) { s += __shfl_xor(s, m); s2 += __shfl_xor(s2, m); }
        const int w = t >> 6;
        if ((t & 63) == 0) { red[w] = s; red[8 + w] = s2; }
        __syncthreads();
        s = 0.f; s2 = 0.f;
#pragma unroll
        for (int i = 0; i < 8; ++i) { s += red[i]; s2 += red[8 + i]; }
        const float mean = s * (1.f / 16384.f);
        const float var  = fmaxf(s2 * (1.f / 16384.f) - mean * mean, 0.f);
        const float rstd = rsqrtf(var + 1e-6f);

        float ga[8], be[8];
#pragma unroll
        for (int it = 0; it < 8; ++it) {
            const int gc = g * 16 + hi * 8 + it;
            ga[it] = gamma[gc] * rstd;
            be[it] = beta[gc] - mean * ga[it];
        }
#pragma unroll
        for (int j = 0; j < 4; ++j) {
            bf16x8 o;
#pragma unroll
            for (int it = 0; it < 8; ++it)
                o[it] = (bf16_t)(v[it][j] * ga[it] + be[it]);
            *(bf16x8*)(xnT + ((size_t)b * 1024 + tl * 4 + j) * 512 + g * 16 + hi * 8) = o;
        }
    } else {
        // weight cast fp32 -> bf16
        const int i = ((blk - 768) * 512 + t) * 4;
#pragma unroll
        for (int j = 0; j < 4; ++j) {
            Wqkv[i + j]          = (bf16_t)wq[i + j];
            Wqkv[262144 + i + j] = (bf16_t)wk[i + j];
            Wqkv[524288 + i + j] = (bf16_t)wv[i + j];
            Wp[i + j]            = (bf16_t)wp[i + j];
        }
    }
}

// ---------------------------------------------------------------------------
// K2/K4: GEMM (3-buffer ring + counted vmcnt).
// ---------------------------------------------------------------------------
__global__ __launch_bounds__(256) void gemm_bt(
    const bf16_t* __restrict__ A, const bf16_t* __restrict__ Bt, int mode,
    int mtiles,
    const float* __restrict__ bias0, const float* __restrict__ bias1,
    const float* __restrict__ bias2,
    const float* __restrict__ x0, float* __restrict__ outF,
    bf16_t* __restrict__ Qb, bf16_t* __restrict__ Kb, bf16_t* __restrict__ Vb)
{
    const int K  = 512;
    const int g  = blockIdx.x;
    const int xcd = g & 7;
    const int i_  = g >> 3;
    const int m_idx = i_ % mtiles;
    const int n_idx = xcd * 8 + i_ / mtiles;
    const int m0 = m_idx * 128;
    const int n0 = n_idx * 128;
    const int t = threadIdx.x;
    const int l = t & 63, w = t >> 6;
    const int wr = w >> 1, wc = w & 1;
    const int lrow = l & 15, lgrp = l >> 4;

    __shared__ __align__(16) char smem_raw[49152];
    bf16_t* Ct = (bf16_t*)smem_raw;           // [128][136] (34816 B)

    f32x4 acc[4][4];
#pragma unroll
    for (int i = 0; i < 4; ++i)
#pragma unroll
        for (int j = 0; j < 4; ++j) acc[i][j] = (f32x4){0.f, 0.f, 0.f, 0.f};

    const bf16_t* gA0 = A  + (size_t)(m0 + w * 16 + (l >> 2)) * K + (l & 3) * 8;
    const bf16_t* gA1 = gA0 + (size_t)64 * K;
    const bf16_t* gB0 = Bt + (size_t)(n0 + w * 16 + (l >> 2)) * K + (l & 3) * 8;
    const bf16_t* gB1 = gB0 + (size_t)64 * K;

#define STAGE(s, k0) do {                                                   \
    bf16_t* As_ = (bf16_t*)(smem_raw + (s) * 16384);                        \
    bf16_t* Bs_ = (bf16_t*)(smem_raw + (s) * 16384 + 8192);                 \
    GLDS16(gA0 + (k0), As_ + w * 512);                                      \
    GLDS16(gA1 + (k0), As_ + 2048 + w * 512);                               \
    GLDS16(gB0 + (k0), Bs_ + w * 512);                                      \
    GLDS16(gB1 + (k0), Bs_ + 2048 + w * 512); } while (0)

    STAGE(0, 0);
    STAGE(1, 32);

#pragma unroll
    for (int tk = 0; tk < 16; ++tk) {
        if (tk < 15) asm volatile("s_waitcnt vmcnt(4)" ::: "memory");
        else         asm volatile("s_waitcnt vmcnt(0)" ::: "memory");
        __builtin_amdgcn_s_barrier();
        __builtin_amdgcn_sched_barrier(0);
        if (tk + 2 < 16) STAGE((tk + 2) % 3, (tk + 2) * 32);
        const bf16_t* Asb = (const bf16_t*)(smem_raw + (tk % 3) * 16384);
        const bf16_t* Bsb = Asb + 4096;
        bf16x8 af[4], bfr[4];
#pragma unroll
        for (int ms = 0; ms < 4; ++ms)
            af[ms] = *(const bf16x8*)&Asb[(wr * 64 + ms * 16 + lrow) * 32 + lgrp * 8];
#pragma unroll
        for (int ns = 0; ns < 4; ++ns)
            bfr[ns] = *(const bf16x8*)&Bsb[(wc * 64 + ns * 16 + lrow) * 32 + lgrp * 8];
        __builtin_amdgcn_s_setprio(1);
#pragma unroll
        for (int ms = 0; ms < 4; ++ms)
#pragma unroll
            for (int ns = 0; ns < 4; ++ns)
                acc[ms][ns] = MFMA16(af[ms], bfr[ns], acc[ms][ns]);
        __builtin_amdgcn_s_setprio(0);
    }
#undef STAGE

    if (mode == 0) {
        const int which = m0 >> 9;
        const int mq = (m0 >> 7) & 3;
        const float* bias = (which == 0) ? bias0 : (which == 1) ? bias1 : bias2;
        const float scl = (which == 0) ? 0.125f * LOG2E : 1.0f;
        const int b   = n_idx >> 3;
        const int nn0 = (n_idx & 7) * 128;

        __syncthreads();
        if (which < 2) {
            bf16_t* Qk = (which == 0) ? Qb : Kb;
#pragma unroll
            for (int ms = 0; ms < 4; ++ms) {
                const int ml = wr * 64 + ms * 16 + lgrp * 4;
#pragma unroll
                for (int ns = 0; ns < 4; ++ns) {
                    const int nl = wc * 64 + ns * 16 + lrow;
                    bf16x4 pk;
#pragma unroll
                    for (int j = 0; j < 4; ++j)
                        pk[j] = (bf16_t)((acc[ms][ns][j] + bias[mq * 128 + ml + j]) * scl);
                    *(bf16x4*)&Ct[nl * 136 + ml] = pk;
                }
            }
            __syncthreads();
#pragma unroll
            for (int it = 0; it < 8; ++it) {
                const int idx = it * 256 + t;
                const int token = idx >> 4, oc = idx & 15;
                const bf16x8 vv8 = *(const bf16x8*)&Ct[token * 136 + oc * 8];
                const int head = mq * 2 + (oc >> 3);
                const int d = (oc & 7) * 8;
                *(bf16x8*)(Qk + (((size_t)b * 8 + head) * 1024 + nn0 + token) * 64 + d) = vv8;
            }
        } else {
#pragma unroll
            for (int ms = 0; ms < 4; ++ms) {
                const int ml = wr * 64 + ms * 16 + lgrp * 4;
#pragma unroll
                for (int ns = 0; ns < 4; ++ns) {
                    const int nl = wc * 64 + ns * 16 + lrow;
#pragma unroll
                    for (int j = 0; j < 4; ++j)
                        Ct[(ml + j) * 136 + nl] =
                            (bf16_t)(acc[ms][ns][j] + bias[mq * 128 + ml + j]);
                }
            }
            __syncthreads();
#pragma unroll
            for (int it = 0; it < 8; ++it) {
                const int idx = it * 256 + t;
                const int o = idx >> 4, nc = idx & 15;
                const bf16x8 vv8 = *(const bf16x8*)&Ct[o * 136 + nc * 8];
                const int head = mq * 2 + (o >> 6);
                const int d = o & 63;
                *(bf16x8*)(Vb + (((size_t)b * 8 + head) * 64 + d) * 1024 + nn0 + nc * 8) = vv8;
            }
        }
    } else {
#pragma unroll
        for (int ms = 0; ms < 4; ++ms) {
#pragma unroll
            for (int ns = 0; ns < 4; ++ns) {
                const int c  = m0 + wr * 64 + ms * 16 + lgrp * 4;
                const int np = n0 + wc * 64 + ns * 16 + lrow;
                const int b = np >> 10, n = np & 1023;
#pragma unroll
                for (int j = 0; j < 4; ++j) {
                    const size_t idx = ((size_t)b * 512 + c + j) * 1024 + n;
                    outF[idx] = acc[ms][ns][j] + bias0[c + j] + x0[idx];
                }
            }
        }
    }
}

// ---------------------------------------------------------------------------
// K3: fused attention — best measured variant (16x16 MFMA, swapped-QK,
// max-free base-2 softmax, 8-wave/128q blocks, double-tile staging, MFMA
// row-sum, no setprio).  42.7us measured; 5 structural alternatives all
// landed 42.7-47us -> this is the decomposition's practical floor.
// Grid: x = bh (XCD ~ h -> K/V+bias L2-resident), y = q-tile/128.
// ---------------------------------------------------------------------------
__global__ __launch_bounds__(512) void attn_kernel(
    const bf16_t* __restrict__ Qb, const bf16_t* __restrict__ Kb,
    const bf16_t* __restrict__ Vb, const bf16_t* __restrict__ Bias2,
    bf16_t* __restrict__ Xo)
{
    const int bh = blockIdx.x;
    const int h  = bh & 7;
    const int q0 = blockIdx.y * 128;
    const int t = threadIdx.x;
    const int w = t >> 6, l = t & 63;
    const int lrow = l & 15, lgrp = l >> 4;

    __shared__ __align__(16) bf16_t Ks[128][72];     // [nk][d]
    __shared__ __align__(16) bf16_t Vs[64][136];     // [d][nk]
    __shared__ __align__(16) bf16_t Ps[8][16][72];   // per-wave [q][nk]

    const int qrow = q0 + w * 16 + lrow;
    const bf16_t* qbase = Qb + ((size_t)bh * 1024 + qrow) * 64;
    const bf16x8 qf0 = *(const bf16x8*)(qbase + lgrp * 8);
    const bf16x8 qf1 = *(const bf16x8*)(qbase + 32 + lgrp * 8);

    const bf16_t* bb = Bias2 + (((size_t)h * 64 + (q0 >> 4) + w) * 64) * 256;

    bf16x8 ones;
#pragma unroll
    for (int i = 0; i < 8; ++i) ones[i] = (bf16_t)1.0f;

    f32x4 oacc[4], tsacc = (f32x4){0.f, 0.f, 0.f, 0.f};
#pragma unroll
    for (int j = 0; j < 4; ++j) oacc[j] = (f32x4){0.f, 0.f, 0.f, 0.f};

    const int sr2 = t >> 3;
    const int sc2 = (t & 7) * 8;
    const bf16_t* Kg = Kb + ((size_t)bh * 1024 + sr2) * 64 + sc2;   // [nk][d]
    const bf16_t* Vg = Vb + ((size_t)bh * 64 + sr2) * 1024 + sc2;   // [d][nk]

    // prologue: prefetch double-tile 0 (K 128 rows, V 128 cols, bias x8)
    bf16x8 kv0 = *(const bf16x8*)(Kg);
    bf16x8 kv1 = *(const bf16x8*)(Kg + (size_t)64 * 64);
    bf16x8 vv0 = *(const bf16x8*)(Vg);
    bf16x8 vv1 = *(const bf16x8*)(Vg + 64);
    bf16x4 bA[8], bB[8];
#pragma unroll
    for (int k = 0; k < 8; ++k)
        bA[k] = *(const bf16x4*)(bb + (size_t)(k * 64 + l) * 4);

    auto dtile = [&](int it, bf16x4 (&bcur)[8], bf16x4 (&bnxt)[8]) {
        const int nk0 = it * 128;
        __syncthreads();                 // prev double-tile's LDS reads done
        *(bf16x8*)&Ks[sr2][sc2]      = kv0;
        *(bf16x8*)&Ks[64 + sr2][sc2] = kv1;
        *(bf16x8*)&Vs[sr2][sc2]      = vv0;
        *(bf16x8*)&Vs[sr2][64 + sc2] = vv1;
        __syncthreads();                 // LDS visible to all waves
        if (it < 7) {                    // prefetch double-tile it+1
            const int nkn = nk0 + 128;
#pragma unroll
            for (int k = 0; k < 8; ++k)
                bnxt[k] = *(const bf16x4*)(bb + (size_t)((((nkn >> 4)) + k) * 64 + l) * 4);
            kv0 = *(const bf16x8*)(Kg + (size_t)nkn * 64);
            kv1 = *(const bf16x8*)(Kg + (size_t)(nkn + 64) * 64);
            vv0 = *(const bf16x8*)(Vg + nkn);
            vv1 = *(const bf16x8*)(Vg + nkn + 64);
        }

#pragma unroll
        for (int st = 0; st < 2; ++st) {
            // S^T = K Q^T (+bias from regs):  D[row = nk_local][col = q]
            f32x4 s[4];
#pragma unroll
            for (int ns = 0; ns < 4; ++ns) {
                const bf16x4 bc = bcur[st * 4 + ns];
                f32x4 z = (f32x4){(float)bc[0], (float)bc[1],
                                  (float)bc[2], (float)bc[3]};
                const bf16x8 kf0 = *(const bf16x8*)&Ks[st * 64 + ns * 16 + lrow][lgrp * 8];
                const bf16x8 kf1 = *(const bf16x8*)&Ks[st * 64 + ns * 16 + lrow][32 + lgrp * 8];
                z = MFMA16(kf0, qf0, z);
                z = MFMA16(kf1, qf1, z);
                s[ns] = z;
            }
            // p = exp2(s); pack to Ps[q][nk]  (row-sum handled by MFMA below)
#pragma unroll
            for (int ns = 0; ns < 4; ++ns) {
                bf16x4 pk;
                pk[0] = (bf16_t)exp2f(s[ns][0]);
                pk[1] = (bf16_t)exp2f(s[ns][1]);
                pk[2] = (bf16_t)exp2f(s[ns][2]);
                pk[3] = (bf16_t)exp2f(s[ns][3]);
                *(bf16x4*)&Ps[w][lrow][ns * 16 + lgrp * 4] = pk;
            }
            const bf16x8 pf0 = *(const bf16x8*)&Ps[w][lrow][lgrp * 8];
            const bf16x8 pf1 = *(const bf16x8*)&Ps[w][lrow][32 + lgrp * 8];
            // ts(q) += sum_nk P  (ones-A MFMA: every row of D = row-sum)
            tsacc = MFMA16(ones, pf0, tsacc);
            tsacc = MFMA16(ones, pf1, tsacc);
            // PV:  out^T[d][q] += V^T[d][nk] * P^T[nk][q]
#pragma unroll
            for (int ds = 0; ds < 4; ++ds) {
                const bf16x8 vf0 = *(const bf16x8*)&Vs[ds * 16 + lrow][st * 64 + lgrp * 8];
                const bf16x8 vf1 = *(const bf16x8*)&Vs[ds * 16 + lrow][st * 64 + 32 + lgrp * 8];
                oacc[ds] = MFMA16(vf0, pf0, oacc[ds]);
                oacc[ds] = MFMA16(vf1, pf1, oacc[ds]);
            }
        }
    };

    for (int it2 = 0; it2 < 8; it2 += 2) {
        dtile(it2,     bA, bB);
        dtile(it2 + 1, bB, bA);
    }

    // tsacc holds full ts(q) in every element for this lane's q = lrow
    const float inv = 1.0f / tsacc[0];

    const int b = bh >> 3;
    const int q = q0 + w * 16 + lrow;
    bf16_t* xrow = Xo + ((size_t)b * 1024 + q) * 512 + h * 64;
#pragma unroll
    for (int ds = 0; ds < 4; ++ds) {
        bf16x4 o4;
#pragma unroll
        for (int j = 0; j < 4; ++j) o4[j] = (bf16_t)(oacc[ds][j] * inv);
        *(bf16x4*)(xrow + ds * 16 + lgrp * 4) = o4;
    }
}

// ---------------------------------------------------------------------------
extern "C" void kernel_launch(void* const* d_in, const int* in_sizes, int n_in,
                              void* d_out, int out_size, void* d_ws, size_t ws_size,
                              hipStream_t stream)
{
    const float* x     = (const float*)d_in[0];
    const float* gamma = (const float*)d_in[3];
    const float* beta  = (const float*)d_in[4];
    const float* wq    = (const float*)d_in[5];
    const float* bq    = (const float*)d_in[6];
    const float* wk    = (const float*)d_in[7];
    const float* bk    = (const float*)d_in[8];
    const float* wv    = (const float*)d_in[9];
    const float* bv    = (const float*)d_in[10];
    const float* wp    = (const float*)d_in[11];
    const float* bp    = (const float*)d_in[12];
    const float* pos   = (const float*)d_in[13];
    float* out = (float*)d_out;

    size_t off = 0;
    char* wsb = (char*)d_ws;
    auto alloc = [&](size_t bytes) { char* p = wsb + off; off += bytes; return p; };
    bf16_t* Wqkv  = (bf16_t*)alloc((size_t)1536 * 512 * 2);
    bf16_t* Wp    = (bf16_t*)alloc((size_t)512 * 512 * 2);
    bf16_t* xnT   = (bf16_t*)alloc((size_t)8192 * 512 * 2);
    bf16_t* Qb    = (bf16_t*)alloc((size_t)8192 * 512 * 2);
    bf16_t* Kb    = (bf16_t*)alloc((size_t)8192 * 512 * 2);
    bf16_t* Vb    = (bf16_t*)alloc((size_t)8192 * 512 * 2);
    bf16_t* Xo    = (bf16_t*)alloc((size_t)8192 * 512 * 2);
    bf16_t* Bias2 = (bf16_t*)alloc((size_t)8 * 64 * 64 * 64 * 4 * 2);

    hipLaunchKernelGGL(prep_kernel, dim3(896), dim3(512), 0, stream,
                       wq, wk, wv, wp, Wqkv, Wp, pos, Bias2,
                       x, gamma, beta, xnT);
    hipLaunchKernelGGL(gemm_bt, dim3(768), dim3(256), 0, stream,
                       Wqkv, xnT, 0, 12, bq, bk, bv,
                       nullptr, nullptr, Qb, Kb, Vb);
    hipLaunchKernelGGL(attn_kernel, dim3(64, 8), dim3(512), 0, stream,
                       Qb, Kb, Vb, Bias2, Xo);
    hipLaunchKernelGGL(gemm_bt, dim3(256), dim3(256), 0, stream,
                       Wp, Xo, 1, 4, bp, nullptr, nullptr,
                       x, out, nullptr, nullptr, nullptr);
}